// Round 1
// baseline (34171.402 us; speedup 1.0000x reference)
//
#include <hip/hip_runtime.h>
#include <math.h>

// ESN recurrence, persistent-kernel design.
// T=1000, B=64, I=80, H=1024, LEAK=0.5.
// Grid = 4 groups (16 batch rows each) x 64 H-tiles (16 H rows each) = 256 blocks,
// 256 threads, 1 block/CU (142 KB LDS). W slice LDS-resident; h exchanged through
// global ws with a per-group 64-block barrier each step.

#define T_STEPS 1000
#define NB      64
#define NI      80
#define NH      1024
#define KCAT    (NH + NI)      // 1104 = concat [h | x_t]
#define KC4     (KCAT / 4)     // 276 float4 per row
#define LSTR    1108           // padded LDS row stride in floats (%4==0, breaks bank stride)
#define NGROUPS 4
#define BTILE   16             // batch rows per group
#define HTILE   16             // H rows per block
#define NTHR    256
#define LDS_BYTES ((HTILE + BTILE) * LSTR * 4)   // 141,824 B

__global__ __launch_bounds__(NTHR, 1) void esn_persistent(
    const float* __restrict__ x,        // [T,B,I]
    const int*   __restrict__ lengths,  // [B] descending
    const float* __restrict__ W_ih,     // [H,I]
    const float* __restrict__ W_hh,     // [H,H]
    float* __restrict__ out,            // [T,B,H]
    float*       h_buf,                 // ws: [2][B][H] fp32, zero-inited
    unsigned*    bar)                   // ws: [NGROUPS*32], zero-inited
{
    extern __shared__ float lds[];
    float* Wc = lds;                    // [HTILE][LSTR] : W_hh row ++ W_ih row
    float* hx = lds + HTILE * LSTR;     // [BTILE][LSTR] : h_t row  ++ x_t row

    const int tid   = threadIdx.x;
    const int bid   = blockIdx.x;
    const int g     = bid >> 6;         // 0..3
    const int htile = bid & 63;         // 0..63
    const int hi0   = htile * HTILE;
    const int gb0   = g * BTILE;

    // ---- load resident weight slice: rows hi0..hi0+15 of [W_hh | W_ih] ----
    for (int idx = tid; idx < HTILE * KC4; idx += NTHR) {
        int r  = idx / KC4;
        int c4 = idx % KC4;
        float4 v;
        if (c4 < NH / 4)
            v = ((const float4*)(W_hh + (size_t)(hi0 + r) * NH))[c4];
        else
            v = ((const float4*)(W_ih + (size_t)(hi0 + r) * NI))[c4 - NH / 4];
        *(float4*)(&Wc[r * LSTR + c4 * 4]) = v;
    }

    const int bl   = tid >> 4;          // local batch row 0..15
    const int il   = tid & 15;          // local H row    0..15
    const int brow = gb0 + bl;
    const int hrow = hi0 + il;
    const int len_b   = lengths[brow];
    const int max_len = lengths[gb0];   // descending-sorted => group max, block-uniform

    unsigned* cnt = bar + g * 32;       // 128B-spaced per-group counter

    const float4* wrow4 = (const float4*)(&Wc[il * LSTR]);
    const float4* hrow4 = (const float4*)(&hx[bl * LSTR]);

    __syncthreads();                    // Wc ready

    for (int t = 0; t < max_len; ++t) {
        const float* h_cur = h_buf + (size_t)(t & 1) * (NB * NH);
        float*       h_nxt = h_buf + (size_t)((t + 1) & 1) * (NB * NH);

        // ---- stage [h_cur | x_t] for this group's 16 batch rows ----
        for (int idx = tid; idx < BTILE * KC4; idx += NTHR) {
            int r  = idx / KC4;
            int c4 = idx % KC4;
            float4 v;
            if (c4 < NH / 4)
                v = ((const float4*)(h_cur + (size_t)(gb0 + r) * NH))[c4];
            else
                v = ((const float4*)(x + ((size_t)t * NB + gb0 + r) * NI))[c4 - NH / 4];
            *(float4*)(&hx[r * LSTR + c4 * 4]) = v;
        }
        __syncthreads();

        // ---- dot over K=1104 ----
        float acc = 0.f;
        #pragma unroll 4
        for (int k = 0; k < KC4; ++k) {
            float4 w = wrow4[k];
            float4 h = hrow4[k];
            acc = fmaf(w.x, h.x, acc);
            acc = fmaf(w.y, h.y, acc);
            acc = fmaf(w.z, h.z, acc);
            acc = fmaf(w.w, h.w, acc);
        }

        float hp = hx[bl * LSTR + hrow];   // previous h for this (b, i)
        float hn, y;
        if (t < len_b) {
            hn = 0.5f * hp + 0.5f * tanhf(acc);
            y  = hn;
        } else {
            hn = hp;                        // frozen
            y  = 0.f;                       // packed output zero past length
        }
        h_nxt[(size_t)brow * NH + hrow] = hn;
        out[((size_t)t * NB + brow) * NH + hrow] = y;

        // ---- per-group barrier: all 64 blocks of group g ----
        __builtin_amdgcn_fence(__ATOMIC_RELEASE, "agent"); // push h stores device-visible
        __syncthreads();                                   // all waves fenced, hx reads done
        if (tid == 0) {
            __hip_atomic_fetch_add(cnt, 1u, __ATOMIC_RELAXED, __HIP_MEMORY_SCOPE_AGENT);
            const unsigned target = (unsigned)(t + 1) * 64u;
            while (__hip_atomic_load(cnt, __ATOMIC_RELAXED, __HIP_MEMORY_SCOPE_AGENT) < target)
                __builtin_amdgcn_s_sleep(1);
        }
        __syncthreads();
        __builtin_amdgcn_fence(__ATOMIC_ACQUIRE, "agent"); // invalidate caches for fresh h
    }

    // ---- tail: whole group past its max length -> outputs are zeros ----
    for (int t = max_len; t < T_STEPS; ++t)
        out[((size_t)t * NB + brow) * NH + hrow] = 0.f;
}

extern "C" void kernel_launch(void* const* d_in, const int* in_sizes, int n_in,
                              void* d_out, int out_size, void* d_ws, size_t ws_size,
                              hipStream_t stream) {
    const float* x       = (const float*)d_in[0];
    const int*   lengths = (const int*)  d_in[1];
    const float* W_ih    = (const float*)d_in[2];
    const float* W_hh    = (const float*)d_in[3];
    float*       out     = (float*)d_out;

    float*    h_buf = (float*)d_ws;                                   // 512 KB
    unsigned* bar   = (unsigned*)((char*)d_ws + 2 * NB * NH * sizeof(float));

    // zero h0 (initial state) + barrier counters; ws is re-poisoned before each launch
    hipMemsetAsync(d_ws, 0, 2 * NB * NH * sizeof(float) + NGROUPS * 32 * sizeof(unsigned),
                   stream);

    // opt in to >64KB dynamic LDS (160 KB/CU on gfx950)
    hipFuncSetAttribute((const void*)esn_persistent,
                        hipFuncAttributeMaxDynamicSharedMemorySize, LDS_BYTES);

    esn_persistent<<<dim3(NGROUPS * 64), dim3(NTHR), LDS_BYTES, stream>>>(
        x, lengths, W_ih, W_hh, out, h_buf, bar);
}

// Round 2
// 19776.141 us; speedup vs baseline: 1.7279x; 1.7279x over previous
//
#include <hip/hip_runtime.h>
#include <math.h>

// ESN recurrence, persistent-kernel design, round 2.
// T=1000, B=64, I=80, H=1024, LEAK=0.5.
// Grid = 4 groups (16 batch rows) x 64 H-tiles (16 H rows) = 256 blocks, 256 thr,
// 1 block/CU (142 KB LDS). W slice LDS-resident.
// R2: NO agent fences (they lower to buffer_wbl2/buffer_inv = full per-XCD L2
// writeback/invalidate, per block per step — the r1 bottleneck). All cross-block
// data (h ping-pong, arrival flags) uses sc0sc1-coherent atomics at the LLC;
// ordering via explicit s_waitcnt + __syncthreads. Barrier = 64 per-block flags
// polled by 64 threads in parallel (no serialized RMW chain).

#define T_STEPS 1000
#define NB      64
#define NI      80
#define NH      1024
#define KCAT    (NH + NI)      // 1104 = concat [h | x_t]
#define KC4     (KCAT / 4)     // 276 float4 per row
#define LSTR    1108           // padded LDS row stride in floats
#define NGROUPS 4
#define BTILE   16             // batch rows per group
#define HTILE   16             // H rows per block
#define NTHR    256
#define LDS_BYTES ((HTILE + BTILE) * LSTR * 4)   // 141,824 B

__global__ __launch_bounds__(NTHR, 1) void esn_persistent(
    const float* __restrict__ x,        // [T,B,I]
    const int*   __restrict__ lengths,  // [B] descending
    const float* __restrict__ W_ih,     // [H,I]
    const float* __restrict__ W_hh,     // [H,H]
    float* __restrict__ out,            // [T,B,H]
    float*       h_buf,                 // ws: [2][B][H] fp32, zero-inited
    unsigned*    flags)                 // ws: [NGROUPS*64], zero-inited
{
    extern __shared__ float lds[];
    float* Wc = lds;                    // [HTILE][LSTR] : W_hh row ++ W_ih row
    float* hx = lds + HTILE * LSTR;     // [BTILE][LSTR] : h_t row  ++ x_t row

    const int tid   = threadIdx.x;
    const int bid   = blockIdx.x;
    const int g     = bid >> 6;         // 0..3
    const int htile = bid & 63;         // 0..63
    const int hi0   = htile * HTILE;
    const int gb0   = g * BTILE;

    // ---- load resident weight slice: rows hi0..hi0+15 of [W_hh | W_ih] ----
    for (int idx = tid; idx < HTILE * KC4; idx += NTHR) {
        int r  = idx / KC4;
        int c4 = idx % KC4;
        float4 v;
        if (c4 < NH / 4)
            v = ((const float4*)(W_hh + (size_t)(hi0 + r) * NH))[c4];
        else
            v = ((const float4*)(W_ih + (size_t)(hi0 + r) * NI))[c4 - NH / 4];
        *(float4*)(&Wc[r * LSTR + c4 * 4]) = v;
    }

    const int bl   = tid >> 4;          // local batch row 0..15
    const int il   = tid & 15;          // local H row    0..15
    const int brow = gb0 + bl;
    const int hrow = hi0 + il;
    const int len_b   = lengths[brow];
    const int max_len = lengths[gb0];   // descending-sorted => group max, block-uniform

    unsigned* gflags = flags + g * 64;

    const float4* wrow4 = (const float4*)(&Wc[il * LSTR]);
    const float4* hrow4 = (const float4*)(&hx[bl * LSTR]);

    __syncthreads();                    // Wc ready

    for (int t = 0; t < max_len; ++t) {
        const float* h_cur = h_buf + (size_t)(t & 1) * (NB * NH);
        float*       h_nxt = h_buf + (size_t)((t + 1) & 1) * (NB * NH);

        // ---- stage [h_cur | x_t] for this group's 16 batch rows ----
        // h part: coherent 8B loads from LLC (sc0sc1) — never trusts stale L2.
        {
            const unsigned long long* h8 =
                (const unsigned long long*)(h_cur + (size_t)gb0 * NH);
            for (int j = tid; j < BTILE * (NH / 2); j += NTHR) {
                int r  = j >> 9;              // j / 512
                int c2 = j & 511;             // 8B chunk within row
                unsigned long long v = __hip_atomic_load(
                    h8 + ((size_t)r * (NH / 2) + c2),
                    __ATOMIC_RELAXED, __HIP_MEMORY_SCOPE_AGENT);
                *(unsigned long long*)(&hx[r * LSTR + c2 * 2]) = v;
            }
        }
        // x part: read-only input, normal cached float4 loads.
        for (int j = tid; j < BTILE * (NI / 4); j += NTHR) {
            int r  = j / (NI / 4);
            int c4 = j % (NI / 4);
            float4 v = ((const float4*)(x + ((size_t)t * NB + gb0 + r) * NI))[c4];
            *(float4*)(&hx[r * LSTR + NH + c4 * 4]) = v;
        }
        __syncthreads();

        // ---- dot over K=1104, 4 independent accumulator chains ----
        float a0 = 0.f, a1 = 0.f, a2 = 0.f, a3 = 0.f;
        #pragma unroll 4
        for (int k = 0; k < KC4; ++k) {
            float4 w = wrow4[k];
            float4 h = hrow4[k];
            a0 = fmaf(w.x, h.x, a0);
            a1 = fmaf(w.y, h.y, a1);
            a2 = fmaf(w.z, h.z, a2);
            a3 = fmaf(w.w, h.w, a3);
        }
        float acc = (a0 + a1) + (a2 + a3);

        float hp = hx[bl * LSTR + hrow];   // previous h for this (b, i)
        float hn, y;
        if (t < len_b) {
            hn = 0.5f * hp + 0.5f * tanhf(acc);
            y  = hn;
        } else {
            hn = hp;                        // frozen
            y  = 0.f;                       // packed output zero past length
        }
        // h store: coherent (sc0sc1) — completes at the LLC, visible device-wide.
        __hip_atomic_store(&h_nxt[(size_t)brow * NH + hrow], hn,
                           __ATOMIC_RELAXED, __HIP_MEMORY_SCOPE_AGENT);
        out[((size_t)t * NB + brow) * NH + hrow] = y;    // normal store (write-only)

        // ---- per-group barrier: 64 per-block flags, parallel poll ----
        __builtin_amdgcn_s_waitcnt(0);   // this wave's h stores complete at LLC
        __syncthreads();                 // => all waves' stores complete
        if (tid == 0)
            __hip_atomic_store(&gflags[htile], (unsigned)(t + 1),
                               __ATOMIC_RELAXED, __HIP_MEMORY_SCOPE_AGENT);
        if (tid < 64) {
            while (__hip_atomic_load(&gflags[tid],
                                     __ATOMIC_RELAXED, __HIP_MEMORY_SCOPE_AGENT)
                   < (unsigned)(t + 1))
                __builtin_amdgcn_s_sleep(1);
        }
        __syncthreads();
    }

    // ---- tail: whole group past its max length -> outputs are zeros ----
    for (int t = max_len; t < T_STEPS; ++t)
        out[((size_t)t * NB + brow) * NH + hrow] = 0.f;
}

extern "C" void kernel_launch(void* const* d_in, const int* in_sizes, int n_in,
                              void* d_out, int out_size, void* d_ws, size_t ws_size,
                              hipStream_t stream) {
    const float* x       = (const float*)d_in[0];
    const int*   lengths = (const int*)  d_in[1];
    const float* W_ih    = (const float*)d_in[2];
    const float* W_hh    = (const float*)d_in[3];
    float*       out     = (float*)d_out;

    float*    h_buf = (float*)d_ws;                                   // 512 KB
    unsigned* flags = (unsigned*)((char*)d_ws + 2 * NB * NH * sizeof(float));

    // zero h0 (initial state) + flags; ws is re-poisoned before each launch
    hipMemsetAsync(d_ws, 0,
                   2 * NB * NH * sizeof(float) + NGROUPS * 64 * sizeof(unsigned),
                   stream);

    hipFuncSetAttribute((const void*)esn_persistent,
                        hipFuncAttributeMaxDynamicSharedMemorySize, LDS_BYTES);

    esn_persistent<<<dim3(NGROUPS * 64), dim3(NTHR), LDS_BYTES, stream>>>(
        x, lengths, W_ih, W_hh, out, h_buf, flags);
}

// Round 3
// 10852.211 us; speedup vs baseline: 3.1488x; 1.8223x over previous
//
#include <hip/hip_runtime.h>
#include <math.h>

// ESN recurrence, persistent-kernel design, round 3.
// T=1000, B=64, I=80, H=1024, LEAK=0.5.
// Grid = 4 groups (16 batch rows) x 64 H-tiles (16 H rows) = 256 blocks.
// R3: 1024 threads/block (16 waves = 4 waves/SIMD) with K split 4-ways per
// output; partial dots combined via LDS. Rationale: r2 ran 1 wave/SIMD, so
// ds_read latency (~120cyc) and LLC load latency were fully exposed
// (VALUBusy 21%, everything idle). 4x TLP hides it; LDS traffic unchanged.

#define T_STEPS 1000
#define NB      64
#define NI      80
#define NH      1024
#define KCAT    (NH + NI)      // 1104 = concat [h | x_t]
#define KC4     (KCAT / 4)     // 276 float4 per row
#define KQ4     (KC4 / 4)      // 69 float4 per k-quarter
#define LSTR    1108           // padded LDS row stride in floats
#define NGROUPS 4
#define BTILE   16             // batch rows per group
#define HTILE   16             // H rows per block
#define NTHR    1024
#define LDS_BYTES (((HTILE + BTILE) * LSTR + NTHR) * 4)   // 145,920 B

__global__ __launch_bounds__(NTHR, 1) void esn_persistent(
    const float* __restrict__ x,        // [T,B,I]
    const int*   __restrict__ lengths,  // [B] descending
    const float* __restrict__ W_ih,     // [H,I]
    const float* __restrict__ W_hh,     // [H,H]
    float* __restrict__ out,            // [T,B,H]
    float*       h_buf,                 // ws: [2][B][H] fp32, zero-inited
    unsigned*    flags)                 // ws: [NGROUPS*64], zero-inited
{
    extern __shared__ float lds[];
    float* Wc   = lds;                     // [HTILE][LSTR] : W_hh row ++ W_ih row
    float* hx   = lds + HTILE * LSTR;      // [BTILE][LSTR] : h_t row  ++ x_t row
    float* part = lds + (HTILE + BTILE) * LSTR;  // [4][256] k-quarter partials

    const int tid   = threadIdx.x;
    const int bid   = blockIdx.x;
    const int g     = bid >> 6;         // 0..3
    const int htile = bid & 63;         // 0..63
    const int hi0   = htile * HTILE;
    const int gb0   = g * BTILE;

    // ---- load resident weight slice: rows hi0..hi0+15 of [W_hh | W_ih] ----
    for (int idx = tid; idx < HTILE * KC4; idx += NTHR) {
        int r  = idx / KC4;
        int c4 = idx % KC4;
        float4 v;
        if (c4 < NH / 4)
            v = ((const float4*)(W_hh + (size_t)(hi0 + r) * NH))[c4];
        else
            v = ((const float4*)(W_ih + (size_t)(hi0 + r) * NI))[c4 - NH / 4];
        *(float4*)(&Wc[r * LSTR + c4 * 4]) = v;
    }

    const int il = tid & 15;            // local H row   0..15
    const int bl = (tid >> 4) & 15;     // local batch   0..15
    const int q  = tid >> 8;            // k-quarter     0..3
    const int brow = gb0 + bl;
    const int hrow = hi0 + il;
    const int len_b   = lengths[brow];
    const int max_len = lengths[gb0];   // descending-sorted => group max, block-uniform

    unsigned* gflags = flags + g * 64;

    const float4* wq = (const float4*)(Wc + il * LSTR) + q * KQ4;
    const float4* hq = (const float4*)(hx + bl * LSTR) + q * KQ4;

    __syncthreads();                    // Wc ready

    for (int t = 0; t < max_len; ++t) {
        const float* h_cur = h_buf + (size_t)(t & 1) * (NB * NH);
        float*       h_nxt = h_buf + (size_t)((t + 1) & 1) * (NB * NH);

        // ---- stage [h_cur | x_t] for this group's 16 batch rows ----
        // h: coherent 8B loads from the LLC (sc0sc1) — 8 per thread, pipelined.
        {
            const unsigned long long* h8 =
                (const unsigned long long*)(h_cur + (size_t)gb0 * NH);
            for (int j = tid; j < BTILE * (NH / 2); j += NTHR) {
                int r  = j >> 9;              // j / 512
                int c2 = j & 511;
                unsigned long long v = __hip_atomic_load(
                    h8 + ((size_t)r * (NH / 2) + c2),
                    __ATOMIC_RELAXED, __HIP_MEMORY_SCOPE_AGENT);
                *(unsigned long long*)(&hx[r * LSTR + c2 * 2]) = v;
            }
        }
        // x: read-only input, normal cached float4 loads.
        for (int j = tid; j < BTILE * (NI / 4); j += NTHR) {
            int r  = j / (NI / 4);
            int c4 = j % (NI / 4);
            float4 v = ((const float4*)(x + ((size_t)t * NB + gb0 + r) * NI))[c4];
            *(float4*)(&hx[r * LSTR + NH + c4 * 4]) = v;
        }
        __syncthreads();

        // ---- quarter-dot over 69 float4s, 4 independent chains ----
        float a0 = 0.f, a1 = 0.f, a2 = 0.f, a3 = 0.f;
        #pragma unroll 3
        for (int k = 0; k < KQ4; ++k) {
            float4 w = wq[k];
            float4 h = hq[k];
            a0 = fmaf(w.x, h.x, a0);
            a1 = fmaf(w.y, h.y, a1);
            a2 = fmaf(w.z, h.z, a2);
            a3 = fmaf(w.w, h.w, a3);
        }
        part[tid] = (a0 + a1) + (a2 + a3);
        __syncthreads();

        // ---- combine quarters, activate, publish (threads 0..255) ----
        if (tid < 256) {
            float acc = (part[tid] + part[tid + 256])
                      + (part[tid + 512] + part[tid + 768]);
            float hp = hx[bl * LSTR + hrow];   // previous h for this (b,i)
            float hn, y;
            if (t < len_b) {
                hn = 0.5f * hp + 0.5f * tanhf(acc);
                y  = hn;
            } else {
                hn = hp;                        // frozen
                y  = 0.f;                       // packed output zero past length
            }
            // coherent store — completes at LLC, visible device-wide
            __hip_atomic_store(&h_nxt[(size_t)brow * NH + hrow], hn,
                               __ATOMIC_RELAXED, __HIP_MEMORY_SCOPE_AGENT);
            out[((size_t)t * NB + brow) * NH + hrow] = y;
        }

        // ---- per-group barrier: 64 per-block flags, parallel poll ----
        __builtin_amdgcn_s_waitcnt(0);   // each wave's stores complete at LLC
        __syncthreads();                 // => all waves' stores complete
        if (tid == 0)
            __hip_atomic_store(&gflags[htile], (unsigned)(t + 1),
                               __ATOMIC_RELAXED, __HIP_MEMORY_SCOPE_AGENT);
        if (tid < 64) {
            while (__hip_atomic_load(&gflags[tid],
                                     __ATOMIC_RELAXED, __HIP_MEMORY_SCOPE_AGENT)
                   < (unsigned)(t + 1))
                __builtin_amdgcn_s_sleep(1);
        }
        __syncthreads();
    }

    // ---- tail: whole group past its max length -> outputs are zeros ----
    for (int j = tid; j < (T_STEPS - max_len) * 256; j += NTHR) {
        int t = max_len + (j >> 8);
        int o = j & 255;
        int b = gb0 + (o >> 4);
        int i = hi0 + (o & 15);
        out[((size_t)t * NB + b) * NH + i] = 0.f;
    }
}

extern "C" void kernel_launch(void* const* d_in, const int* in_sizes, int n_in,
                              void* d_out, int out_size, void* d_ws, size_t ws_size,
                              hipStream_t stream) {
    const float* x       = (const float*)d_in[0];
    const int*   lengths = (const int*)  d_in[1];
    const float* W_ih    = (const float*)d_in[2];
    const float* W_hh    = (const float*)d_in[3];
    float*       out     = (float*)d_out;

    float*    h_buf = (float*)d_ws;                                   // 512 KB
    unsigned* flags = (unsigned*)((char*)d_ws + 2 * NB * NH * sizeof(float));

    // zero h0 (initial state) + flags; ws is re-poisoned before each launch
    hipMemsetAsync(d_ws, 0,
                   2 * NB * NH * sizeof(float) + NGROUPS * 64 * sizeof(unsigned),
                   stream);

    hipFuncSetAttribute((const void*)esn_persistent,
                        hipFuncAttributeMaxDynamicSharedMemorySize, LDS_BYTES);

    esn_persistent<<<dim3(NGROUPS * 64), dim3(NTHR), LDS_BYTES, stream>>>(
        x, lengths, W_ih, W_hh, out, h_buf, flags);
}